// Round 3
// baseline (3105.811 us; speedup 1.0000x reference)
//
#include <hip/hip_runtime.h>
#include <stdint.h>

typedef uint16_t u16;
typedef __attribute__((ext_vector_type(8))) short short8;
typedef __attribute__((ext_vector_type(4))) float f32x4;
typedef __attribute__((ext_vector_type(4))) u16 u16x4;

__device__ __forceinline__ u16 f2bf(float f) {
  union { float f; uint32_t i; } v; v.f = f;
  uint32_t r = v.i + 0x7fffu + ((v.i >> 16) & 1u);
  return (u16)(r >> 16);
}
__device__ __forceinline__ int imin(int a, int b) { return a < b ? a : b; }

// async global->LDS, 16B per lane; LDS dest is wave-uniform base + lane*16
#define GLD_LDS(gp, lp) __builtin_amdgcn_global_load_lds( \
    (__attribute__((address_space(1))) void*)(uintptr_t)(gp), \
    (__attribute__((address_space(3))) void*)(lp), 16, 0, 0)

// ---------------- constants ----------------
#define BATCH 16
#define SEQ 257
#define DIM 1024
#define HEADS 16
#define DHEAD 64
#define FFDIM 4096
#define MROWS (BATCH * SEQ)   // 4112
#define SPAD 288              // padded S for attn K-dim (multiple of 32)
#define KC 608                // padded conv K (3*14*14=588 -> 608)

enum { EPI_PATCH = 0, EPI_QK = 1, EPI_VT = 2, EPI_RES = 3, EPI_GELU = 4 };

struct GemmP {
  const u16* A; const u16* B;
  const float* bias;
  int lda, ldb, M, N, K;
  void* out;
  const float* aux;  // pos_emb for EPI_PATCH
};

// ---------------- GEMM: C = A[M,K] * B[N,K]^T (+bias) with fused epilogue ----
// 128x128 tile, 256 threads (4 waves, 2x2), mfma 16x16x32 bf16, BK=32.
template <int EPI>
__global__ __launch_bounds__(256) void gemm_bt(GemmP p) {
  __shared__ __align__(16) u16 sA[128 * 32];
  __shared__ __align__(16) u16 sB[128 * 32];
  const int tid = threadIdx.x;
  const int w = tid >> 6, l = tid & 63, quad = l >> 4, lr = l & 15;
  const int wr = w >> 1, wc = w & 1;
  const int m0 = blockIdx.y * 128, n0 = blockIdx.x * 128;
  const u16* A = p.A;
  const u16* B = p.B;

  // staging: 2 issues each; f = tid + i*256; row = f>>2, 16B segment = f&3
  const int f0 = tid, f1 = tid + 256;
  const int ar0 = f0 >> 2, as0 = f0 & 3, ar1 = f1 >> 2, as1 = f1 & 3;
  const long aoff0 = (long)imin(m0 + ar0, p.M - 1) * p.lda + (as0 << 3);
  const long aoff1 = (long)imin(m0 + ar1, p.M - 1) * p.lda + (as1 << 3);
  const long boff0 = (long)imin(n0 + ar0, p.N - 1) * p.ldb + (as0 << 3);
  const long boff1 = (long)imin(n0 + ar1, p.N - 1) * p.ldb + (as1 << 3);

  f32x4 acc[4][4];
#pragma unroll
  for (int i = 0; i < 4; ++i)
#pragma unroll
    for (int j = 0; j < 4; ++j) acc[i][j] = (f32x4){0.f, 0.f, 0.f, 0.f};

  for (int k0 = 0; k0 < p.K; k0 += 32) {
    __syncthreads();
    GLD_LDS(A + aoff0 + k0, &sA[f0 * 8]);
    GLD_LDS(A + aoff1 + k0, &sA[f1 * 8]);
    GLD_LDS(B + boff0 + k0, &sB[f0 * 8]);
    GLD_LDS(B + boff1 + k0, &sB[f1 * 8]);
    __syncthreads();
    short8 af[4], bg[4];
#pragma unroll
    for (int t = 0; t < 4; ++t) {
      af[t] = *(const short8*)&sA[(wr * 64 + t * 16 + lr) * 32 + quad * 8];
      bg[t] = *(const short8*)&sB[(wc * 64 + t * 16 + lr) * 32 + quad * 8];
    }
#pragma unroll
    for (int mt = 0; mt < 4; ++mt)
#pragma unroll
      for (int nt = 0; nt < 4; ++nt)
        acc[mt][nt] = __builtin_amdgcn_mfma_f32_16x16x32_bf16(af[mt], bg[nt], acc[mt][nt], 0, 0, 0);
  }

  // epilogue: C/D layout row = quad*4+r, col = lr
#pragma unroll
  for (int mt = 0; mt < 4; ++mt) {
#pragma unroll
    for (int r = 0; r < 4; ++r) {
      const int gm = m0 + wr * 64 + mt * 16 + quad * 4 + r;
      if (gm >= p.M) continue;
#pragma unroll
      for (int nt = 0; nt < 4; ++nt) {
        const int gn = n0 + wc * 64 + nt * 16 + lr;
        if (gn >= p.N) continue;
        float v = acc[mt][nt][r];
        if (p.bias) v += p.bias[gn];
        if constexpr (EPI == EPI_PATCH) {
          // gm = b*256 + patch, gn = d; write X fp32 + pos_emb
          const int b = gm >> 8, pp = gm & 255;
          ((float*)p.out)[((long)(b * SEQ + 1 + pp)) * DIM + gn] =
              v + p.aux[(1 + pp) * DIM + gn];
        } else if constexpr (EPI == EPI_QK) {
          const int b = gm / SEQ, s = gm % SEQ;
          const int h = gn >> 6, d = gn & 63;
          ((u16*)p.out)[(((long)(b * HEADS + h) * SEQ + s)) * DHEAD + d] = f2bf(v);
        } else if constexpr (EPI == EPI_VT) {
          const int b = gm / SEQ, s = gm % SEQ;
          const int h = gn >> 6, d = gn & 63;
          ((u16*)p.out)[((long)(b * HEADS + h) * DHEAD + d) * SPAD + s] = f2bf(v);
        } else if constexpr (EPI == EPI_RES) {
          float* o = (float*)p.out;
          o[(long)gm * p.N + gn] += v;
        } else if constexpr (EPI == EPI_GELU) {
          const float g = v / (1.f + __expf(-1.702f * v));
          ((u16*)p.out)[(long)gm * p.N + gn] = f2bf(g);
        }
      }
    }
  }
}

// ---------------- LayerNorm: fp32 X row -> bf16 out --------------------------
__global__ __launch_bounds__(256) void ln_k(const float* __restrict__ X,
                                            const float* __restrict__ w,
                                            const float* __restrict__ b,
                                            u16* __restrict__ O) {
  const int row = blockIdx.x, tid = threadIdx.x;
  const float4* xr = (const float4*)(X + (long)row * DIM);
  float4 v = xr[tid];
  float s = v.x + v.y + v.z + v.w;
  float s2 = v.x * v.x + v.y * v.y + v.z * v.z + v.w * v.w;
  for (int o = 32; o; o >>= 1) { s += __shfl_xor(s, o); s2 += __shfl_xor(s2, o); }
  __shared__ float red[8];
  const int wv = tid >> 6, l = tid & 63;
  if (l == 0) { red[wv] = s; red[4 + wv] = s2; }
  __syncthreads();
  s = red[0] + red[1] + red[2] + red[3];
  s2 = red[4] + red[5] + red[6] + red[7];
  const float mean = s * (1.f / DIM);
  const float var = s2 * (1.f / DIM) - mean * mean;
  const float rs = rsqrtf(var + 1e-5f);
  const int c = tid * 4;
  const float4 wv4 = *(const float4*)(w + c);
  const float4 bv4 = *(const float4*)(b + c);
  u16x4 o4;
  o4.x = f2bf((v.x - mean) * rs * wv4.x + bv4.x);
  o4.y = f2bf((v.y - mean) * rs * wv4.y + bv4.y);
  o4.z = f2bf((v.z - mean) * rs * wv4.z + bv4.z);
  o4.w = f2bf((v.w - mean) * rs * wv4.w + bv4.w);
  *(u16x4*)(O + (long)row * DIM + c) = o4;
}

// ---------------- fused attention: scores + softmax + P.V --------------------
// grid: (BH=256, qtiles=17); block 256 (4 waves). One block = 16 q-rows.
__global__ __launch_bounds__(256) void attn_k(const u16* __restrict__ Q,
                                              const u16* __restrict__ Kx,
                                              const u16* __restrict__ Vt,
                                              u16* __restrict__ Ctx) {
  const int bh = blockIdx.x;
  const int q0 = blockIdx.y * 16;
  __shared__ float S[16][292];
  __shared__ __align__(16) u16 P[16][SPAD];
  const int tid = threadIdx.x, w = tid >> 6, l = tid & 63, quad = l >> 4, lr = l & 15;
  const u16* Qb = Q + (long)bh * SEQ * DHEAD;
  const u16* Kb = Kx + (long)bh * SEQ * DHEAD;
  const u16* Vb = Vt + (long)bh * DHEAD * SPAD;
  int qm = q0 + lr; if (qm > SEQ - 1) qm = SEQ - 1;
  const short8 aq0 = *(const short8*)(Qb + qm * DHEAD + quad * 8);
  const short8 aq1 = *(const short8*)(Qb + qm * DHEAD + 32 + quad * 8);
  // --- scores: each wave one 16-col block per ct step ---
  for (int ct = 0; ct < 5; ++ct) {
    const int cn = ct * 64 + w * 16 + lr;
    const int cc = cn > SEQ - 1 ? SEQ - 1 : cn;
    const short8 b0 = *(const short8*)(Kb + cc * DHEAD + quad * 8);
    const short8 b1 = *(const short8*)(Kb + cc * DHEAD + 32 + quad * 8);
    f32x4 acc = (f32x4){0.f, 0.f, 0.f, 0.f};
    acc = __builtin_amdgcn_mfma_f32_16x16x32_bf16(aq0, b0, acc, 0, 0, 0);
    acc = __builtin_amdgcn_mfma_f32_16x16x32_bf16(aq1, b1, acc, 0, 0, 0);
    if (cn < SEQ) {
#pragma unroll
      for (int r = 0; r < 4; ++r) S[quad * 4 + r][cn] = acc[r] * 0.125f;
    }
  }
  __syncthreads();
  // --- softmax: wave w owns rows w*4..w*4+3 ---
#pragma unroll
  for (int rr = 0; rr < 4; ++rr) {
    const int m = w * 4 + rr;
    float mx = -1e30f;
    for (int c = l; c < SEQ; c += 64) mx = fmaxf(mx, S[m][c]);
    for (int o = 32; o; o >>= 1) mx = fmaxf(mx, __shfl_xor(mx, o));
    float sum = 0.f;
    for (int c = l; c < SEQ; c += 64) {
      const float e = __expf(S[m][c] - mx);
      S[m][c] = e;
      sum += e;
    }
    for (int o = 32; o; o >>= 1) sum += __shfl_xor(sum, o);
    const float inv = 1.f / sum;
    for (int c = l; c < SPAD; c += 64) P[m][c] = (c < SEQ) ? f2bf(S[m][c] * inv) : (u16)0;
  }
  __syncthreads();
  // --- P.V: wave w computes d-chunk w*16..w*16+15 for all 16 q rows ---
  f32x4 acc = (f32x4){0.f, 0.f, 0.f, 0.f};
  for (int k0 = 0; k0 < SPAD; k0 += 32) {
    const short8 ap = *(const short8*)&P[lr][k0 + quad * 8];
    const short8 bv = *(const short8*)(Vb + (long)(w * 16 + lr) * SPAD + k0 + quad * 8);
    acc = __builtin_amdgcn_mfma_f32_16x16x32_bf16(ap, bv, acc, 0, 0, 0);
  }
  const int b = bh >> 4, h = bh & 15;
#pragma unroll
  for (int r = 0; r < 4; ++r) {
    const int q = q0 + quad * 4 + r;
    if (q < SEQ)
      Ctx[((long)(b * SEQ + q)) * DIM + h * DHEAD + w * 16 + lr] = f2bf(acc[r]);
  }
}

// ---------------- fp32 -> bf16 weight conversion ------------------------------
__global__ void f2b_k(const float* __restrict__ src, u16* __restrict__ dst, int n4) {
  const int i = blockIdx.x * 256 + threadIdx.x;
  if (i >= n4) return;
  const float4 v = ((const float4*)src)[i];
  u16x4 o;
  o.x = f2bf(v.x); o.y = f2bf(v.y); o.z = f2bf(v.z); o.w = f2bf(v.w);
  ((u16x4*)dst)[i] = o;
}

// ---------------- small helpers ----------------------------------------------
__global__ void im2col_k(const float* __restrict__ pv, u16* __restrict__ out) {
  const long i = (long)blockIdx.x * 256 + threadIdx.x;
  if (i >= (long)4096 * KC) return;
  const int col = (int)(i % KC);
  const long row = i / KC;
  u16 val = 0;
  if (col < 588) {
    const int b = (int)(row >> 8), p = (int)(row & 255);
    const int py = p >> 4, px = p & 15;
    const int c = col / 196, rem = col % 196;
    const int ky = rem / 14, kx = rem % 14;
    val = f2bf(pv[(((long)b * 3 + c) * 224 + (py * 14 + ky)) * 224 + (px * 14 + kx)]);
  }
  out[i] = val;
}

__global__ void pwpad_k(const float* __restrict__ pw, u16* __restrict__ out) {
  const int i = blockIdx.x * 256 + threadIdx.x;
  if (i >= DIM * KC) return;
  const int col = i % KC, row = i / KC;
  out[i] = (col < 588) ? f2bf(pw[row * 588 + col]) : (u16)0;
}

__global__ void cls_k(const float* __restrict__ cls, const float* __restrict__ pos,
                      float* __restrict__ X) {
  const int i = blockIdx.x * 256 + threadIdx.x;  // 16*1024
  const int b = i >> 10, d = i & 1023;
  X[((long)b * SEQ) * DIM + d] = cls[d] + pos[d];
}

// zero the Vt s-padding (s=257..287) once per call so poison never feeds MFMA
__global__ void vtpad_k(u16* __restrict__ Vt) {
  const int i = blockIdx.x * 256 + threadIdx.x;  // 256*64*31 = 507904
  if (i >= 256 * 64 * 31) return;
  const int dall = i / 31, s = SEQ + i % 31;
  Vt[(long)dall * SPAD + s] = 0;
}

__global__ void out_k(const float* __restrict__ X, float* __restrict__ O) {
  const int i = blockIdx.x * 256 + threadIdx.x;
  ((float4*)O)[i] = ((const float4*)X)[i];
}

// ---------------- workspace layout (bytes), total ~102.0 MB ------------------
#define OFF_X 0L                 // fp32 residual [4112,1024]  16,842,752
#define OFF_H 16842752L          // bf16 LN out  [4112,1024]    8,421,376
#define OFF_Q 25264128L          // bf16 [BH,257,64]            8,421,376
#define OFF_K 33685504L          // bf16 [BH,257,64]            8,421,376
#define OFF_VT 42106880L         // bf16 [BH,64,288]            9,437,184
#define OFF_CTX 51544064L        // bf16 [4112,1024]            8,421,376
#define OFF_FF 59965440L         // bf16 [4112,4096]           33,685,504
#define OFF_W 93650944L          // bf16 weight slot            8,388,608 (end 102,039,552)
#define OFF_IM OFF_FF            // bf16 [4096,608] aliases FF (used pre-loop only)
#define OFF_PW (OFF_FF + 4980736L) // bf16 [1024,608] aliases FF

extern "C" void kernel_launch(void* const* d_in, const int* in_sizes, int n_in,
                              void* d_out, int out_size, void* d_ws, size_t ws_size,
                              hipStream_t stream) {
  const float* pv = (const float*)d_in[0];
  const float* patch_w = (const float*)d_in[1];
  const float* class_emb = (const float*)d_in[2];
  const float* pos_emb = (const float*)d_in[3];
  const float* ln1_w = (const float*)d_in[4];
  const float* ln1_b = (const float*)d_in[5];
  const float* q_w = (const float*)d_in[6];
  const float* q_b = (const float*)d_in[7];
  const float* k_w = (const float*)d_in[8];
  const float* k_b = (const float*)d_in[9];
  const float* v_w = (const float*)d_in[10];
  const float* v_b = (const float*)d_in[11];
  const float* o_w = (const float*)d_in[12];
  const float* o_b = (const float*)d_in[13];
  const float* ln2_w = (const float*)d_in[14];
  const float* ln2_b = (const float*)d_in[15];
  const float* fc1_w = (const float*)d_in[16];
  const float* fc1_b = (const float*)d_in[17];
  const float* fc2_w = (const float*)d_in[18];
  const float* fc2_b = (const float*)d_in[19];

  char* ws = (char*)d_ws;
  float* X = (float*)(ws + OFF_X);
  u16* Hb = (u16*)(ws + OFF_H);
  u16* Qb = (u16*)(ws + OFF_Q);
  u16* Kb = (u16*)(ws + OFF_K);
  u16* Vt = (u16*)(ws + OFF_VT);
  u16* Ctx = (u16*)(ws + OFF_CTX);
  u16* FFh = (u16*)(ws + OFF_FF);
  u16* Wb = (u16*)(ws + OFF_W);
  u16* Im = (u16*)(ws + OFF_IM);
  u16* Pw = (u16*)(ws + OFF_PW);

  const int NSQ4 = DIM * DIM / 4;        // 262144 fp32x4 groups per DxD weight
  const int NFF4 = FFDIM * DIM / 4;      // 1048576 per FF weight
  const int GSQ = (NSQ4 + 255) / 256, GFF = (NFF4 + 255) / 256;

  // embeddings
  im2col_k<<<(4096 * KC + 255) / 256, 256, 0, stream>>>(pv, Im);
  pwpad_k<<<(DIM * KC + 255) / 256, 256, 0, stream>>>(patch_w, Pw);
  cls_k<<<(BATCH * DIM) / 256, 256, 0, stream>>>(class_emb, pos_emb, X);
  vtpad_k<<<(256 * 64 * 31 + 255) / 256, 256, 0, stream>>>(Vt);
  {
    GemmP g = {};
    g.A = Im; g.lda = KC; g.B = Pw; g.ldb = KC; g.bias = nullptr;
    g.M = 4096; g.N = DIM; g.K = KC; g.out = X; g.aux = pos_emb;
    gemm_bt<EPI_PATCH><<<dim3(8, 32, 1), 256, 0, stream>>>(g);
  }

  for (int idx = 0; idx < 6; ++idx) {
    ln_k<<<MROWS, 256, 0, stream>>>(X, ln1_w + idx * DIM, ln1_b + idx * DIM, Hb);
    {
      GemmP g = {};
      g.A = Hb; g.lda = DIM; g.B = Wb; g.ldb = DIM;
      g.M = MROWS; g.N = DIM; g.K = DIM;
      f2b_k<<<GSQ, 256, 0, stream>>>(q_w + (long)idx * DIM * DIM, Wb, NSQ4);
      g.bias = q_b + idx * DIM; g.out = Qb;
      gemm_bt<EPI_QK><<<dim3(8, 33, 1), 256, 0, stream>>>(g);
      f2b_k<<<GSQ, 256, 0, stream>>>(k_w + (long)idx * DIM * DIM, Wb, NSQ4);
      g.bias = k_b + idx * DIM; g.out = Kb;
      gemm_bt<EPI_QK><<<dim3(8, 33, 1), 256, 0, stream>>>(g);
      f2b_k<<<GSQ, 256, 0, stream>>>(v_w + (long)idx * DIM * DIM, Wb, NSQ4);
      g.bias = v_b + idx * DIM; g.out = Vt;
      gemm_bt<EPI_VT><<<dim3(8, 33, 1), 256, 0, stream>>>(g);
    }
    attn_k<<<dim3(256, 17, 1), 256, 0, stream>>>(Qb, Kb, Vt, Ctx);
    {
      GemmP g = {};
      f2b_k<<<GSQ, 256, 0, stream>>>(o_w + (long)idx * DIM * DIM, Wb, NSQ4);
      g.A = Ctx; g.lda = DIM; g.B = Wb; g.ldb = DIM;
      g.bias = o_b + idx * DIM; g.M = MROWS; g.N = DIM; g.K = DIM; g.out = X;
      gemm_bt<EPI_RES><<<dim3(8, 33, 1), 256, 0, stream>>>(g);
    }
    ln_k<<<MROWS, 256, 0, stream>>>(X, ln2_w + idx * DIM, ln2_b + idx * DIM, Hb);
    {
      GemmP g = {};
      f2b_k<<<GFF, 256, 0, stream>>>(fc1_w + (long)idx * FFDIM * DIM, Wb, NFF4);
      g.A = Hb; g.lda = DIM; g.B = Wb; g.ldb = DIM;
      g.bias = fc1_b + idx * FFDIM; g.M = MROWS; g.N = FFDIM; g.K = DIM; g.out = FFh;
      gemm_bt<EPI_GELU><<<dim3(32, 33, 1), 256, 0, stream>>>(g);
    }
    {
      GemmP g = {};
      f2b_k<<<GFF, 256, 0, stream>>>(fc2_w + (long)idx * DIM * FFDIM, Wb, NFF4);
      g.A = FFh; g.lda = FFDIM; g.B = Wb; g.ldb = FFDIM;
      g.bias = fc2_b + idx * DIM; g.M = MROWS; g.N = DIM; g.K = FFDIM; g.out = X;
      gemm_bt<EPI_RES><<<dim3(8, 33, 1), 256, 0, stream>>>(g);
    }
    // MoD top-k block: x = where(mask, x, x) == identity -> skipped
  }
  out_k<<<(MROWS * DIM / 4) / 256, 256, 0, stream>>>(X, (float*)d_out);
}

// Round 4
// 2571.210 us; speedup vs baseline: 1.2079x; 1.2079x over previous
//
#include <hip/hip_runtime.h>
#include <stdint.h>

typedef uint16_t u16;
typedef __attribute__((ext_vector_type(8))) short short8;
typedef __attribute__((ext_vector_type(4))) float f32x4;
typedef __attribute__((ext_vector_type(4))) u16 u16x4;

__device__ __forceinline__ u16 f2bf(float f) {
  union { float f; uint32_t i; } v; v.f = f;
  uint32_t r = v.i + 0x7fffu + ((v.i >> 16) & 1u);
  return (u16)(r >> 16);
}
__device__ __forceinline__ int imin(int a, int b) { return a < b ? a : b; }

// async global->LDS, 16B per lane; LDS dest is wave-uniform base + lane*16
#define GLD_LDS(gp, lp) __builtin_amdgcn_global_load_lds( \
    (__attribute__((address_space(1))) void*)(uintptr_t)(gp), \
    (__attribute__((address_space(3))) void*)(lp), 16, 0, 0)

// ---------------- constants ----------------
#define BATCH 16
#define SEQ 257
#define DIM 1024
#define HEADS 16
#define DHEAD 64
#define FFDIM 4096
#define MROWS (BATCH * SEQ)   // 4112
#define SPAD 288              // padded S for attn K-dim (multiple of 32)
#define KC 608                // padded conv K (3*14*14=588 -> 608)

enum { EPI_PATCH = 0, EPI_QKV = 1, EPI_RES = 2, EPI_GELU = 3 };

struct GemmP {
  const u16* A; const u16* B;
  const float* bias;
  int lda, ldb, M, N, K;
  void* out;
  void* out2; void* out3;     // K, Vt for EPI_QKV
  const float* aux;           // pos_emb for EPI_PATCH
};

// ---------------- GEMM: C = A[M,K] * B[N,K]^T (+bias), fused epilogue --------
// Tile (32*MT) x 128, 256 threads (4 waves, 2x2), mfma 16x16x32 bf16, BK=32.
// MT=4 -> 128x128 (big GEMMs); MT=2 -> 64x128 (N=1024 GEMMs, 2 blocks/CU+).
template <int EPI, int MT>
__global__ __launch_bounds__(256) void gemm_bt(GemmP p) {
  constexpr int TM = MT * 32;
  constexpr int AISS = MT / 2;
  __shared__ __align__(16) u16 sA[TM * 32];
  __shared__ __align__(16) u16 sB[128 * 32];
  const int tid = threadIdx.x;
  const int w = tid >> 6, l = tid & 63, quad = l >> 4, lr = l & 15;
  const int wr = w >> 1, wc = w & 1;
  const int m0 = blockIdx.y * TM, n0 = blockIdx.x * 128;

  long aoff[AISS];
#pragma unroll
  for (int i = 0; i < AISS; ++i) {
    const int f = tid + i * 256;
    aoff[i] = (long)imin(m0 + (f >> 2), p.M - 1) * p.lda + ((f & 3) << 3);
  }
  long boff[2];
#pragma unroll
  for (int i = 0; i < 2; ++i) {
    const int f = tid + i * 256;
    boff[i] = (long)imin(n0 + (f >> 2), p.N - 1) * p.ldb + ((f & 3) << 3);
  }

  f32x4 acc[MT][4];
#pragma unroll
  for (int i = 0; i < MT; ++i)
#pragma unroll
    for (int j = 0; j < 4; ++j) acc[i][j] = (f32x4){0.f, 0.f, 0.f, 0.f};

  for (int k0 = 0; k0 < p.K; k0 += 32) {
    __syncthreads();
#pragma unroll
    for (int i = 0; i < AISS; ++i)
      GLD_LDS(p.A + aoff[i] + k0, &sA[(tid + i * 256) * 8]);
#pragma unroll
    for (int i = 0; i < 2; ++i)
      GLD_LDS(p.B + boff[i] + k0, &sB[(tid + i * 256) * 8]);
    __syncthreads();
    short8 af[MT], bg[4];
#pragma unroll
    for (int t = 0; t < MT; ++t)
      af[t] = *(const short8*)&sA[(wr * (MT * 16) + t * 16 + lr) * 32 + quad * 8];
#pragma unroll
    for (int t = 0; t < 4; ++t)
      bg[t] = *(const short8*)&sB[(wc * 64 + t * 16 + lr) * 32 + quad * 8];
#pragma unroll
    for (int mt = 0; mt < MT; ++mt)
#pragma unroll
      for (int nt = 0; nt < 4; ++nt)
        acc[mt][nt] = __builtin_amdgcn_mfma_f32_16x16x32_bf16(af[mt], bg[nt], acc[mt][nt], 0, 0, 0);
  }

  // epilogue: C/D layout row = quad*4+r, col = lr
#pragma unroll
  for (int mt = 0; mt < MT; ++mt) {
#pragma unroll
    for (int r = 0; r < 4; ++r) {
      const int gm = m0 + wr * (MT * 16) + mt * 16 + quad * 4 + r;
      if (gm >= p.M) continue;
#pragma unroll
      for (int nt = 0; nt < 4; ++nt) {
        const int gn = n0 + wc * 64 + nt * 16 + lr;
        if (gn >= p.N) continue;
        float v = acc[mt][nt][r];
        if (p.bias) v += p.bias[gn];
        if constexpr (EPI == EPI_PATCH) {
          // gm = b*256 + patch, gn = d; write X fp32 + pos_emb
          const int b = gm >> 8, pp = gm & 255;
          ((float*)p.out)[((long)(b * SEQ + 1 + pp)) * DIM + gn] =
              v + p.aux[(1 + pp) * DIM + gn];
        } else if constexpr (EPI == EPI_QKV) {
          const int b = gm / SEQ, s = gm % SEQ;
          const int seg = gn >> 10, dloc = gn & 1023;
          const int h = dloc >> 6, dd = dloc & 63;
          const u16 val = f2bf(v);
          if (seg == 0)
            ((u16*)p.out)[(((long)(b * HEADS + h) * SEQ + s)) * DHEAD + dd] = val;
          else if (seg == 1)
            ((u16*)p.out2)[(((long)(b * HEADS + h) * SEQ + s)) * DHEAD + dd] = val;
          else
            ((u16*)p.out3)[((long)(b * HEADS + h) * DHEAD + dd) * SPAD + s] = val;
        } else if constexpr (EPI == EPI_RES) {
          float* o = (float*)p.out;
          o[(long)gm * p.N + gn] += v;
        } else if constexpr (EPI == EPI_GELU) {
          const float g = v / (1.f + __expf(-1.702f * v));
          ((u16*)p.out)[(long)gm * p.N + gn] = f2bf(g);
        }
      }
    }
  }
}

// ---------------- LayerNorm: fp32 X row -> bf16 out --------------------------
__global__ __launch_bounds__(256) void ln_k(const float* __restrict__ X,
                                            const float* __restrict__ w,
                                            const float* __restrict__ b,
                                            u16* __restrict__ O) {
  const int row = blockIdx.x, tid = threadIdx.x;
  const float4* xr = (const float4*)(X + (long)row * DIM);
  float4 v = xr[tid];
  float s = v.x + v.y + v.z + v.w;
  float s2 = v.x * v.x + v.y * v.y + v.z * v.z + v.w * v.w;
  for (int o = 32; o; o >>= 1) { s += __shfl_xor(s, o); s2 += __shfl_xor(s2, o); }
  __shared__ float red[8];
  const int wv = tid >> 6, l = tid & 63;
  if (l == 0) { red[wv] = s; red[4 + wv] = s2; }
  __syncthreads();
  s = red[0] + red[1] + red[2] + red[3];
  s2 = red[4] + red[5] + red[6] + red[7];
  const float mean = s * (1.f / DIM);
  const float var = s2 * (1.f / DIM) - mean * mean;
  const float rs = rsqrtf(var + 1e-5f);
  const int c = tid * 4;
  const float4 wv4 = *(const float4*)(w + c);
  const float4 bv4 = *(const float4*)(b + c);
  u16x4 o4;
  o4.x = f2bf((v.x - mean) * rs * wv4.x + bv4.x);
  o4.y = f2bf((v.y - mean) * rs * wv4.y + bv4.y);
  o4.z = f2bf((v.z - mean) * rs * wv4.z + bv4.z);
  o4.w = f2bf((v.w - mean) * rs * wv4.w + bv4.w);
  *(u16x4*)(O + (long)row * DIM + c) = o4;
}

// ---------------- fused attention: scores + softmax + P.V --------------------
// grid: (BH=256, qtiles=17); block 256 (4 waves). One block = 16 q-rows.
__global__ __launch_bounds__(256) void attn_k(const u16* __restrict__ Q,
                                              const u16* __restrict__ Kx,
                                              const u16* __restrict__ Vt,
                                              u16* __restrict__ Ctx) {
  const int bh = blockIdx.x;
  const int q0 = blockIdx.y * 16;
  __shared__ float S[16][292];
  __shared__ __align__(16) u16 P[16][SPAD];
  const int tid = threadIdx.x, w = tid >> 6, l = tid & 63, quad = l >> 4, lr = l & 15;
  const u16* Qb = Q + (long)bh * SEQ * DHEAD;
  const u16* Kb = Kx + (long)bh * SEQ * DHEAD;
  const u16* Vb = Vt + (long)bh * DHEAD * SPAD;
  int qm = q0 + lr; if (qm > SEQ - 1) qm = SEQ - 1;
  const short8 aq0 = *(const short8*)(Qb + qm * DHEAD + quad * 8);
  const short8 aq1 = *(const short8*)(Qb + qm * DHEAD + 32 + quad * 8);
  // --- scores: each wave one 16-col block per ct step ---
  for (int ct = 0; ct < 5; ++ct) {
    const int cn = ct * 64 + w * 16 + lr;
    const int cc = cn > SEQ - 1 ? SEQ - 1 : cn;
    const short8 b0 = *(const short8*)(Kb + cc * DHEAD + quad * 8);
    const short8 b1 = *(const short8*)(Kb + cc * DHEAD + 32 + quad * 8);
    f32x4 acc = (f32x4){0.f, 0.f, 0.f, 0.f};
    acc = __builtin_amdgcn_mfma_f32_16x16x32_bf16(aq0, b0, acc, 0, 0, 0);
    acc = __builtin_amdgcn_mfma_f32_16x16x32_bf16(aq1, b1, acc, 0, 0, 0);
    if (cn < SEQ) {
#pragma unroll
      for (int r = 0; r < 4; ++r) S[quad * 4 + r][cn] = acc[r] * 0.125f;
    }
  }
  __syncthreads();
  // --- softmax: wave w owns rows w*4..w*4+3 ---
#pragma unroll
  for (int rr = 0; rr < 4; ++rr) {
    const int m = w * 4 + rr;
    float mx = -1e30f;
    for (int c = l; c < SEQ; c += 64) mx = fmaxf(mx, S[m][c]);
    for (int o = 32; o; o >>= 1) mx = fmaxf(mx, __shfl_xor(mx, o));
    float sum = 0.f;
    for (int c = l; c < SEQ; c += 64) {
      const float e = __expf(S[m][c] - mx);
      S[m][c] = e;
      sum += e;
    }
    for (int o = 32; o; o >>= 1) sum += __shfl_xor(sum, o);
    const float inv = 1.f / sum;
    for (int c = l; c < SPAD; c += 64) P[m][c] = (c < SEQ) ? f2bf(S[m][c] * inv) : (u16)0;
  }
  __syncthreads();
  // --- P.V: wave w computes d-chunk w*16..w*16+15 for all 16 q rows ---
  f32x4 acc = (f32x4){0.f, 0.f, 0.f, 0.f};
  for (int k0 = 0; k0 < SPAD; k0 += 32) {
    const short8 ap = *(const short8*)&P[lr][k0 + quad * 8];
    const short8 bv = *(const short8*)(Vb + (long)(w * 16 + lr) * SPAD + k0 + quad * 8);
    acc = __builtin_amdgcn_mfma_f32_16x16x32_bf16(ap, bv, acc, 0, 0, 0);
  }
  const int b = bh >> 4, h = bh & 15;
#pragma unroll
  for (int r = 0; r < 4; ++r) {
    const int q = q0 + quad * 4 + r;
    if (q < SEQ)
      Ctx[((long)(b * SEQ + q)) * DIM + h * DHEAD + w * 16 + lr] = f2bf(acc[r]);
  }
}

// ---------------- fp32 -> bf16 weight conversion ------------------------------
__global__ void f2b_k(const float* __restrict__ src, u16* __restrict__ dst, int n4) {
  const int i = blockIdx.x * 256 + threadIdx.x;
  if (i >= n4) return;
  const float4 v = ((const float4*)src)[i];
  u16x4 o;
  o.x = f2bf(v.x); o.y = f2bf(v.y); o.z = f2bf(v.z); o.w = f2bf(v.w);
  ((u16x4*)dst)[i] = o;
}

__global__ void cat3_k(const float* __restrict__ a, const float* __restrict__ b,
                       const float* __restrict__ c, float* __restrict__ o) {
  const int i = blockIdx.x * 256 + threadIdx.x;  // 3072
  o[i] = (i < 1024) ? a[i] : (i < 2048 ? b[i - 1024] : c[i - 2048]);
}

// ---------------- small helpers ----------------------------------------------
__global__ void im2col_k(const float* __restrict__ pv, u16* __restrict__ out) {
  const long i = (long)blockIdx.x * 256 + threadIdx.x;
  if (i >= (long)4096 * KC) return;
  const int col = (int)(i % KC);
  const long row = i / KC;
  u16 val = 0;
  if (col < 588) {
    const int b = (int)(row >> 8), p = (int)(row & 255);
    const int py = p >> 4, px = p & 15;
    const int c = col / 196, rem = col % 196;
    const int ky = rem / 14, kx = rem % 14;
    val = f2bf(pv[(((long)b * 3 + c) * 224 + (py * 14 + ky)) * 224 + (px * 14 + kx)]);
  }
  out[i] = val;
}

__global__ void pwpad_k(const float* __restrict__ pw, u16* __restrict__ out) {
  const int i = blockIdx.x * 256 + threadIdx.x;
  if (i >= DIM * KC) return;
  const int col = i % KC, row = i / KC;
  out[i] = (col < 588) ? f2bf(pw[row * 588 + col]) : (u16)0;
}

__global__ void cls_k(const float* __restrict__ cls, const float* __restrict__ pos,
                      float* __restrict__ X) {
  const int i = blockIdx.x * 256 + threadIdx.x;  // 16*1024
  const int b = i >> 10, d = i & 1023;
  X[((long)b * SEQ) * DIM + d] = cls[d] + pos[d];
}

// zero the Vt s-padding (s=257..287) once per call so poison never feeds MFMA
__global__ void vtpad_k(u16* __restrict__ Vt) {
  const int i = blockIdx.x * 256 + threadIdx.x;  // 256*64*31 = 507904
  if (i >= 256 * 64 * 31) return;
  const int dall = i / 31, s = SEQ + i % 31;
  Vt[(long)dall * SPAD + s] = 0;
}

__global__ void out_k(const float* __restrict__ X, float* __restrict__ O) {
  const int i = blockIdx.x * 256 + threadIdx.x;
  ((float4*)O)[i] = ((const float4*)X)[i];
}

// ---------------- workspace layout (bytes), total ~102.0 MB ------------------
#define OFF_X 0L                 // fp32 residual [4112,1024]  16,842,752
#define OFF_H 16842752L          // bf16 LN out  [4112,1024]    8,421,376
#define OFF_Q 25264128L          // bf16 [BH,257,64]            8,421,376
#define OFF_K 33685504L          // bf16 [BH,257,64]            8,421,376
#define OFF_VT 42106880L         // bf16 [BH,64,288]            9,437,184
#define OFF_CTX 51544064L        // bf16 [4112,1024]            8,421,376
#define OFF_FF 59965440L         // bf16 [4112,4096]           33,685,504
#define OFF_W 93650944L          // bf16 weight slot            8,388,608 (end 102,039,552)
#define OFF_B3 (OFF_W + 6291456L) // fp32 [3072] qkv bias, inside W slot tail
#define OFF_IM OFF_FF            // bf16 [4096,608] aliases FF (used pre-loop only)
#define OFF_PW (OFF_FF + 4980736L) // bf16 [1024,608] aliases FF

extern "C" void kernel_launch(void* const* d_in, const int* in_sizes, int n_in,
                              void* d_out, int out_size, void* d_ws, size_t ws_size,
                              hipStream_t stream) {
  const float* pv = (const float*)d_in[0];
  const float* patch_w = (const float*)d_in[1];
  const float* class_emb = (const float*)d_in[2];
  const float* pos_emb = (const float*)d_in[3];
  const float* ln1_w = (const float*)d_in[4];
  const float* ln1_b = (const float*)d_in[5];
  const float* q_w = (const float*)d_in[6];
  const float* q_b = (const float*)d_in[7];
  const float* k_w = (const float*)d_in[8];
  const float* k_b = (const float*)d_in[9];
  const float* v_w = (const float*)d_in[10];
  const float* v_b = (const float*)d_in[11];
  const float* o_w = (const float*)d_in[12];
  const float* o_b = (const float*)d_in[13];
  const float* ln2_w = (const float*)d_in[14];
  const float* ln2_b = (const float*)d_in[15];
  const float* fc1_w = (const float*)d_in[16];
  const float* fc1_b = (const float*)d_in[17];
  const float* fc2_w = (const float*)d_in[18];
  const float* fc2_b = (const float*)d_in[19];

  char* ws = (char*)d_ws;
  float* X = (float*)(ws + OFF_X);
  u16* Hb = (u16*)(ws + OFF_H);
  u16* Qb = (u16*)(ws + OFF_Q);
  u16* Kb = (u16*)(ws + OFF_K);
  u16* Vt = (u16*)(ws + OFF_VT);
  u16* Ctx = (u16*)(ws + OFF_CTX);
  u16* FFh = (u16*)(ws + OFF_FF);
  u16* Wb = (u16*)(ws + OFF_W);
  float* B3 = (float*)(ws + OFF_B3);
  u16* Im = (u16*)(ws + OFF_IM);
  u16* Pw = (u16*)(ws + OFF_PW);

  const int NSQ4 = DIM * DIM / 4;        // fp32x4 groups per DxD weight
  const int NFF4 = FFDIM * DIM / 4;      // per FF weight
  const int GSQ = (NSQ4 + 255) / 256, GFF = (NFF4 + 255) / 256;

  // embeddings
  im2col_k<<<(4096 * KC + 255) / 256, 256, 0, stream>>>(pv, Im);
  pwpad_k<<<(DIM * KC + 255) / 256, 256, 0, stream>>>(patch_w, Pw);
  cls_k<<<(BATCH * DIM) / 256, 256, 0, stream>>>(class_emb, pos_emb, X);
  vtpad_k<<<(256 * 64 * 31 + 255) / 256, 256, 0, stream>>>(Vt);
  {
    GemmP g = {};
    g.A = Im; g.lda = KC; g.B = Pw; g.ldb = KC; g.bias = nullptr;
    g.M = 4096; g.N = DIM; g.K = KC; g.out = X; g.aux = pos_emb;
    gemm_bt<EPI_PATCH, 2><<<dim3(8, 64, 1), 256, 0, stream>>>(g);
  }

  for (int idx = 0; idx < 6; ++idx) {
    ln_k<<<MROWS, 256, 0, stream>>>(X, ln1_w + idx * DIM, ln1_b + idx * DIM, Hb);
    {
      // fused QKV: B rows [0,1024)=q_w, [1024,2048)=k_w, [2048,3072)=v_w
      f2b_k<<<GSQ, 256, 0, stream>>>(q_w + (long)idx * DIM * DIM, Wb, NSQ4);
      f2b_k<<<GSQ, 256, 0, stream>>>(k_w + (long)idx * DIM * DIM, Wb + DIM * DIM, NSQ4);
      f2b_k<<<GSQ, 256, 0, stream>>>(v_w + (long)idx * DIM * DIM, Wb + 2 * DIM * DIM, NSQ4);
      cat3_k<<<12, 256, 0, stream>>>(q_b + idx * DIM, k_b + idx * DIM, v_b + idx * DIM, B3);
      GemmP g = {};
      g.A = Hb; g.lda = DIM; g.B = Wb; g.ldb = DIM; g.bias = B3;
      g.M = MROWS; g.N = 3 * DIM; g.K = DIM;
      g.out = Qb; g.out2 = Kb; g.out3 = Vt;
      gemm_bt<EPI_QKV, 4><<<dim3(24, 33, 1), 256, 0, stream>>>(g);
    }
    attn_k<<<dim3(256, 17, 1), 256, 0, stream>>>(Qb, Kb, Vt, Ctx);
    {
      GemmP g = {};
      f2b_k<<<GSQ, 256, 0, stream>>>(o_w + (long)idx * DIM * DIM, Wb, NSQ4);
      g.A = Ctx; g.lda = DIM; g.B = Wb; g.ldb = DIM;
      g.bias = o_b + idx * DIM; g.M = MROWS; g.N = DIM; g.K = DIM; g.out = X;
      gemm_bt<EPI_RES, 2><<<dim3(8, 65, 1), 256, 0, stream>>>(g);
    }
    ln_k<<<MROWS, 256, 0, stream>>>(X, ln2_w + idx * DIM, ln2_b + idx * DIM, Hb);
    {
      GemmP g = {};
      f2b_k<<<GFF, 256, 0, stream>>>(fc1_w + (long)idx * FFDIM * DIM, Wb, NFF4);
      g.A = Hb; g.lda = DIM; g.B = Wb; g.ldb = DIM;
      g.bias = fc1_b + idx * FFDIM; g.M = MROWS; g.N = FFDIM; g.K = DIM; g.out = FFh;
      gemm_bt<EPI_GELU, 4><<<dim3(32, 33, 1), 256, 0, stream>>>(g);
    }
    {
      GemmP g = {};
      f2b_k<<<GFF, 256, 0, stream>>>(fc2_w + (long)idx * DIM * FFDIM, Wb, NFF4);
      g.A = FFh; g.lda = FFDIM; g.B = Wb; g.ldb = FFDIM;
      g.bias = fc2_b + idx * DIM; g.M = MROWS; g.N = DIM; g.K = FFDIM; g.out = X;
      gemm_bt<EPI_RES, 2><<<dim3(8, 65, 1), 256, 0, stream>>>(g);
    }
    // MoD top-k block: x = where(mask, x, x) == identity -> skipped
  }
  out_k<<<(MROWS * DIM / 4) / 256, 256, 0, stream>>>(X, (float*)d_out);
}

// Round 5
// 2559.636 us; speedup vs baseline: 1.2134x; 1.0045x over previous
//
#include <hip/hip_runtime.h>
#include <stdint.h>

typedef uint16_t u16;
typedef __attribute__((ext_vector_type(8))) short short8;
typedef __attribute__((ext_vector_type(4))) float f32x4;
typedef __attribute__((ext_vector_type(4))) u16 u16x4;

__device__ __forceinline__ u16 f2bf(float f) {
  union { float f; uint32_t i; } v; v.f = f;
  uint32_t r = v.i + 0x7fffu + ((v.i >> 16) & 1u);
  return (u16)(r >> 16);
}
__device__ __forceinline__ int imin(int a, int b) { return a < b ? a : b; }

// async global->LDS, 16B per lane; LDS dest is wave-uniform base + lane*16
#define GLD_LDS(gp, lp) __builtin_amdgcn_global_load_lds( \
    (__attribute__((address_space(1))) void*)(uintptr_t)(gp), \
    (__attribute__((address_space(3))) void*)(lp), 16, 0, 0)

// ---------------- constants ----------------
#define BATCH 16
#define SEQ 257
#define DIM 1024
#define HEADS 16
#define DHEAD 64
#define FFDIM 4096
#define MROWS (BATCH * SEQ)   // 4112
#define SPAD 288              // padded S for attn K-dim (multiple of 32)
#define KC 640                // padded conv K (3*14*14=588 -> 640, /64)

enum { EPI_PATCH = 0, EPI_QKV = 1, EPI_RES = 2, EPI_GELU = 3 };

struct GemmP {
  const u16* A; const u16* B;
  const float* bias;
  int lda, ldb, M, N, K;
  void* out;
  void* out2; void* out3;     // K, Vt for EPI_QKV
  const float* aux;           // pos_emb for EPI_PATCH
};

// ---------------- GEMM: C = A[M,K] * B[N,K]^T (+bias), fused epilogue --------
// Tile (32*MT) x 128, 256 threads (4 waves, 2x2), mfma 16x16x32 bf16, BK=64.
// LDS K-slab stored as two 32-col panels (keeps the m97 ds_read_b128 bank
// pattern). BK=64 halves barrier-drain count vs BK=32 (m97 plateau mechanism).
template <int EPI, int MT>
__global__ __launch_bounds__(256) void gemm_bt(GemmP p) {
  constexpr int TM = MT * 32;
  constexpr int NA = TM / 32;         // A staging issues (4096B each)
  constexpr int SHA = (MT == 4) ? 9 : 8;
  __shared__ __align__(16) u16 sA[2][TM][32];
  __shared__ __align__(16) u16 sB[2][128][32];
  const int tid = threadIdx.x;
  const int w = tid >> 6, l = tid & 63, quad = l >> 4, lr = l & 15;
  const int wr = w >> 1, wc = w & 1;
  const int m0 = blockIdx.y * TM, n0 = blockIdx.x * 128;

  // staging maps: f -> (panel = f>>SH, row = (f>>2)&(R-1), seg = f&3)
  long aoff[NA];
#pragma unroll
  for (int i = 0; i < NA; ++i) {
    const int f = tid + i * 256;
    const int pnl = f >> SHA, r = (f >> 2) & (TM - 1), s = f & 3;
    aoff[i] = (long)imin(m0 + r, p.M - 1) * p.lda + pnl * 32 + s * 8;
  }
  long boff[4];
#pragma unroll
  for (int i = 0; i < 4; ++i) {
    const int f = tid + i * 256;
    const int pnl = f >> 9, r = (f >> 2) & 127, s = f & 3;
    boff[i] = (long)imin(n0 + r, p.N - 1) * p.ldb + pnl * 32 + s * 8;
  }

  f32x4 acc[MT][4];
#pragma unroll
  for (int i = 0; i < MT; ++i)
#pragma unroll
    for (int j = 0; j < 4; ++j) acc[i][j] = (f32x4){0.f, 0.f, 0.f, 0.f};

  for (int k0 = 0; k0 < p.K; k0 += 64) {
    __syncthreads();
#pragma unroll
    for (int i = 0; i < NA; ++i)
      GLD_LDS(p.A + aoff[i] + k0, (u16*)sA + (tid + i * 256) * 8);
#pragma unroll
    for (int i = 0; i < 4; ++i)
      GLD_LDS(p.B + boff[i] + k0, (u16*)sB + (tid + i * 256) * 8);
    __syncthreads();
    short8 a0[MT], a1[MT], b0[4], b1[4];
#pragma unroll
    for (int t = 0; t < MT; ++t) {
      a0[t] = *(const short8*)&sA[0][wr * (MT * 16) + t * 16 + lr][quad * 8];
      a1[t] = *(const short8*)&sA[1][wr * (MT * 16) + t * 16 + lr][quad * 8];
    }
#pragma unroll
    for (int t = 0; t < 4; ++t) {
      b0[t] = *(const short8*)&sB[0][wc * 64 + t * 16 + lr][quad * 8];
      b1[t] = *(const short8*)&sB[1][wc * 64 + t * 16 + lr][quad * 8];
    }
#pragma unroll
    for (int mt = 0; mt < MT; ++mt)
#pragma unroll
      for (int nt = 0; nt < 4; ++nt) {
        acc[mt][nt] = __builtin_amdgcn_mfma_f32_16x16x32_bf16(a0[mt], b0[nt], acc[mt][nt], 0, 0, 0);
        acc[mt][nt] = __builtin_amdgcn_mfma_f32_16x16x32_bf16(a1[mt], b1[nt], acc[mt][nt], 0, 0, 0);
      }
  }

  // epilogue: C/D layout row = quad*4+r, col = lr
#pragma unroll
  for (int mt = 0; mt < MT; ++mt) {
#pragma unroll
    for (int r = 0; r < 4; ++r) {
      const int gm = m0 + wr * (MT * 16) + mt * 16 + quad * 4 + r;
      if (gm >= p.M) continue;
#pragma unroll
      for (int nt = 0; nt < 4; ++nt) {
        const int gn = n0 + wc * 64 + nt * 16 + lr;
        if (gn >= p.N) continue;
        float v = acc[mt][nt][r];
        if (p.bias) v += p.bias[gn];
        if constexpr (EPI == EPI_PATCH) {
          const int b = gm >> 8, pp = gm & 255;
          ((float*)p.out)[((long)(b * SEQ + 1 + pp)) * DIM + gn] =
              v + p.aux[(1 + pp) * DIM + gn];
        } else if constexpr (EPI == EPI_QKV) {
          const int b = gm / SEQ, s = gm % SEQ;
          const int seg = gn >> 10, dloc = gn & 1023;
          const int h = dloc >> 6, dd = dloc & 63;
          const u16 val = f2bf(v);
          if (seg == 0)
            ((u16*)p.out)[(((long)(b * HEADS + h) * SEQ + s)) * DHEAD + dd] = val;
          else if (seg == 1)
            ((u16*)p.out2)[(((long)(b * HEADS + h) * SEQ + s)) * DHEAD + dd] = val;
          else
            ((u16*)p.out3)[((long)(b * HEADS + h) * DHEAD + dd) * SPAD + s] = val;
        } else if constexpr (EPI == EPI_RES) {
          float* o = (float*)p.out;
          o[(long)gm * p.N + gn] += v;
        } else if constexpr (EPI == EPI_GELU) {
          const float g = v / (1.f + __expf(-1.702f * v));
          ((u16*)p.out)[(long)gm * p.N + gn] = f2bf(g);
        }
      }
    }
  }
}

// ---------------- LayerNorm: fp32 X row -> bf16 out --------------------------
__global__ __launch_bounds__(256) void ln_k(const float* __restrict__ X,
                                            const float* __restrict__ w,
                                            const float* __restrict__ b,
                                            u16* __restrict__ O) {
  const int row = blockIdx.x, tid = threadIdx.x;
  const float4* xr = (const float4*)(X + (long)row * DIM);
  float4 v = xr[tid];
  float s = v.x + v.y + v.z + v.w;
  float s2 = v.x * v.x + v.y * v.y + v.z * v.z + v.w * v.w;
  for (int o = 32; o; o >>= 1) { s += __shfl_xor(s, o); s2 += __shfl_xor(s2, o); }
  __shared__ float red[8];
  const int wv = tid >> 6, l = tid & 63;
  if (l == 0) { red[wv] = s; red[4 + wv] = s2; }
  __syncthreads();
  s = red[0] + red[1] + red[2] + red[3];
  s2 = red[4] + red[5] + red[6] + red[7];
  const float mean = s * (1.f / DIM);
  const float var = s2 * (1.f / DIM) - mean * mean;
  const float rs = rsqrtf(var + 1e-5f);
  const int c = tid * 4;
  const float4 wv4 = *(const float4*)(w + c);
  const float4 bv4 = *(const float4*)(b + c);
  u16x4 o4;
  o4.x = f2bf((v.x - mean) * rs * wv4.x + bv4.x);
  o4.y = f2bf((v.y - mean) * rs * wv4.y + bv4.y);
  o4.z = f2bf((v.z - mean) * rs * wv4.z + bv4.z);
  o4.w = f2bf((v.w - mean) * rs * wv4.w + bv4.w);
  *(u16x4*)(O + (long)row * DIM + c) = o4;
}

// ---------------- fused attention: scores + softmax + P.V --------------------
__global__ __launch_bounds__(256) void attn_k(const u16* __restrict__ Q,
                                              const u16* __restrict__ Kx,
                                              const u16* __restrict__ Vt,
                                              u16* __restrict__ Ctx) {
  const int bh = blockIdx.x;
  const int q0 = blockIdx.y * 16;
  __shared__ float S[16][292];
  __shared__ __align__(16) u16 P[16][SPAD];
  const int tid = threadIdx.x, w = tid >> 6, l = tid & 63, quad = l >> 4, lr = l & 15;
  const u16* Qb = Q + (long)bh * SEQ * DHEAD;
  const u16* Kb = Kx + (long)bh * SEQ * DHEAD;
  const u16* Vb = Vt + (long)bh * DHEAD * SPAD;
  int qm = q0 + lr; if (qm > SEQ - 1) qm = SEQ - 1;
  const short8 aq0 = *(const short8*)(Qb + qm * DHEAD + quad * 8);
  const short8 aq1 = *(const short8*)(Qb + qm * DHEAD + 32 + quad * 8);
  for (int ct = 0; ct < 5; ++ct) {
    const int cn = ct * 64 + w * 16 + lr;
    const int cc = cn > SEQ - 1 ? SEQ - 1 : cn;
    const short8 b0 = *(const short8*)(Kb + cc * DHEAD + quad * 8);
    const short8 b1 = *(const short8*)(Kb + cc * DHEAD + 32 + quad * 8);
    f32x4 acc = (f32x4){0.f, 0.f, 0.f, 0.f};
    acc = __builtin_amdgcn_mfma_f32_16x16x32_bf16(aq0, b0, acc, 0, 0, 0);
    acc = __builtin_amdgcn_mfma_f32_16x16x32_bf16(aq1, b1, acc, 0, 0, 0);
    if (cn < SEQ) {
#pragma unroll
      for (int r = 0; r < 4; ++r) S[quad * 4 + r][cn] = acc[r] * 0.125f;
    }
  }
  __syncthreads();
#pragma unroll
  for (int rr = 0; rr < 4; ++rr) {
    const int m = w * 4 + rr;
    float mx = -1e30f;
    for (int c = l; c < SEQ; c += 64) mx = fmaxf(mx, S[m][c]);
    for (int o = 32; o; o >>= 1) mx = fmaxf(mx, __shfl_xor(mx, o));
    float sum = 0.f;
    for (int c = l; c < SEQ; c += 64) {
      const float e = __expf(S[m][c] - mx);
      S[m][c] = e;
      sum += e;
    }
    for (int o = 32; o; o >>= 1) sum += __shfl_xor(sum, o);
    const float inv = 1.f / sum;
    for (int c = l; c < SPAD; c += 64) P[m][c] = (c < SEQ) ? f2bf(S[m][c] * inv) : (u16)0;
  }
  __syncthreads();
  f32x4 acc = (f32x4){0.f, 0.f, 0.f, 0.f};
  for (int k0 = 0; k0 < SPAD; k0 += 32) {
    const short8 ap = *(const short8*)&P[lr][k0 + quad * 8];
    const short8 bv = *(const short8*)(Vb + (long)(w * 16 + lr) * SPAD + k0 + quad * 8);
    acc = __builtin_amdgcn_mfma_f32_16x16x32_bf16(ap, bv, acc, 0, 0, 0);
  }
  const int b = bh >> 4, h = bh & 15;
#pragma unroll
  for (int r = 0; r < 4; ++r) {
    const int q = q0 + quad * 4 + r;
    if (q < SEQ)
      Ctx[((long)(b * SEQ + q)) * DIM + h * DHEAD + w * 16 + lr] = f2bf(acc[r]);
  }
}

// ---------------- fp32 -> bf16 weight conversion ------------------------------
__global__ void f2b_k(const float* __restrict__ src, u16* __restrict__ dst, int n4) {
  const int i = blockIdx.x * 256 + threadIdx.x;
  if (i >= n4) return;
  const float4 v = ((const float4*)src)[i];
  u16x4 o;
  o.x = f2bf(v.x); o.y = f2bf(v.y); o.z = f2bf(v.z); o.w = f2bf(v.w);
  ((u16x4*)dst)[i] = o;
}

// convert q,k,v weight blocks in one launch: dst rows [0,N)(q) [N,2N)(k) [2N,3N)(v)
__global__ void wcvt3_k(const float* __restrict__ q, const float* __restrict__ k,
                        const float* __restrict__ v, u16* __restrict__ dst, int n4) {
  const int i = blockIdx.x * 256 + threadIdx.x;
  if (i >= 3 * n4) return;
  const float* src; int j;
  if (i < n4) { src = q; j = i; }
  else if (i < 2 * n4) { src = k; j = i - n4; }
  else { src = v; j = i - 2 * n4; }
  const float4 vv = ((const float4*)src)[j];
  u16x4 o;
  o.x = f2bf(vv.x); o.y = f2bf(vv.y); o.z = f2bf(vv.z); o.w = f2bf(vv.w);
  ((u16x4*)dst)[i] = o;
}

__global__ void cat3_k(const float* __restrict__ a, const float* __restrict__ b,
                       const float* __restrict__ c, float* __restrict__ o) {
  const int i = blockIdx.x * 256 + threadIdx.x;  // 3072
  o[i] = (i < 1024) ? a[i] : (i < 2048 ? b[i - 1024] : c[i - 2048]);
}

// ---------------- small helpers ----------------------------------------------
__global__ void im2col_k(const float* __restrict__ pv, u16* __restrict__ out) {
  const long i = (long)blockIdx.x * 256 + threadIdx.x;
  if (i >= (long)4096 * KC) return;
  const int col = (int)(i % KC);
  const long row = i / KC;
  u16 val = 0;
  if (col < 588) {
    const int b = (int)(row >> 8), p = (int)(row & 255);
    const int py = p >> 4, px = p & 15;
    const int c = col / 196, rem = col % 196;
    const int ky = rem / 14, kx = rem % 14;
    val = f2bf(pv[(((long)b * 3 + c) * 224 + (py * 14 + ky)) * 224 + (px * 14 + kx)]);
  }
  out[i] = val;
}

__global__ void pwpad_k(const float* __restrict__ pw, u16* __restrict__ out) {
  const int i = blockIdx.x * 256 + threadIdx.x;
  if (i >= DIM * KC) return;
  const int col = i % KC, row = i / KC;
  out[i] = (col < 588) ? f2bf(pw[row * 588 + col]) : (u16)0;
}

__global__ void cls_k(const float* __restrict__ cls, const float* __restrict__ pos,
                      float* __restrict__ X) {
  const int i = blockIdx.x * 256 + threadIdx.x;  // 16*1024
  const int b = i >> 10, d = i & 1023;
  X[((long)b * SEQ) * DIM + d] = cls[d] + pos[d];
}

// zero the Vt s-padding (s=257..287) so poison never feeds MFMA
__global__ void vtpad_k(u16* __restrict__ Vt) {
  const int i = blockIdx.x * 256 + threadIdx.x;  // 256*64*31 = 507904
  if (i >= 256 * 64 * 31) return;
  const int dall = i / 31, s = SEQ + i % 31;
  Vt[(long)dall * SPAD + s] = 0;
}

__global__ void out_k(const float* __restrict__ X, float* __restrict__ O) {
  const int i = blockIdx.x * 256 + threadIdx.x;
  ((float4*)O)[i] = ((const float4*)X)[i];
}

// ---------------- workspace layout (bytes), total ~102.0 MB ------------------
#define OFF_X 0L                 // fp32 residual [4112,1024]  16,842,752
#define OFF_H 16842752L          // bf16 LN out  [4112,1024]    8,421,376
#define OFF_Q 25264128L          // bf16 [BH,257,64]            8,421,376
#define OFF_K 33685504L          // bf16 [BH,257,64]            8,421,376
#define OFF_VT 42106880L         // bf16 [BH,64,288]            9,437,184
#define OFF_CTX 51544064L        // bf16 [4112,1024]            8,421,376
#define OFF_FF 59965440L         // bf16 [4112,4096]           33,685,504
#define OFF_W 93650944L          // bf16 weight slot            8,388,608 (end 102,039,552)
#define OFF_B3 (OFF_W + 6291456L) // fp32 [3072] qkv bias, inside W slot tail
#define OFF_IM OFF_FF            // bf16 [4096,640] aliases FF (pre-loop only)
#define OFF_PW (OFF_FF + 5242880L) // bf16 [1024,640] aliases FF

extern "C" void kernel_launch(void* const* d_in, const int* in_sizes, int n_in,
                              void* d_out, int out_size, void* d_ws, size_t ws_size,
                              hipStream_t stream) {
  const float* pv = (const float*)d_in[0];
  const float* patch_w = (const float*)d_in[1];
  const float* class_emb = (const float*)d_in[2];
  const float* pos_emb = (const float*)d_in[3];
  const float* ln1_w = (const float*)d_in[4];
  const float* ln1_b = (const float*)d_in[5];
  const float* q_w = (const float*)d_in[6];
  const float* q_b = (const float*)d_in[7];
  const float* k_w = (const float*)d_in[8];
  const float* k_b = (const float*)d_in[9];
  const float* v_w = (const float*)d_in[10];
  const float* v_b = (const float*)d_in[11];
  const float* o_w = (const float*)d_in[12];
  const float* o_b = (const float*)d_in[13];
  const float* ln2_w = (const float*)d_in[14];
  const float* ln2_b = (const float*)d_in[15];
  const float* fc1_w = (const float*)d_in[16];
  const float* fc1_b = (const float*)d_in[17];
  const float* fc2_w = (const float*)d_in[18];
  const float* fc2_b = (const float*)d_in[19];

  char* ws = (char*)d_ws;
  float* X = (float*)(ws + OFF_X);
  u16* Hb = (u16*)(ws + OFF_H);
  u16* Qb = (u16*)(ws + OFF_Q);
  u16* Kb = (u16*)(ws + OFF_K);
  u16* Vt = (u16*)(ws + OFF_VT);
  u16* Ctx = (u16*)(ws + OFF_CTX);
  u16* FFh = (u16*)(ws + OFF_FF);
  u16* Wb = (u16*)(ws + OFF_W);
  float* B3 = (float*)(ws + OFF_B3);
  u16* Im = (u16*)(ws + OFF_IM);
  u16* Pw = (u16*)(ws + OFF_PW);

  const int NSQ4 = DIM * DIM / 4;
  const int NFF4 = FFDIM * DIM / 4;
  const int GSQ = (NSQ4 + 255) / 256, GFF = (NFF4 + 255) / 256;

  // embeddings
  im2col_k<<<(4096 * KC + 255) / 256, 256, 0, stream>>>(pv, Im);
  pwpad_k<<<(DIM * KC + 255) / 256, 256, 0, stream>>>(patch_w, Pw);
  cls_k<<<(BATCH * DIM) / 256, 256, 0, stream>>>(class_emb, pos_emb, X);
  vtpad_k<<<(256 * 64 * 31 + 255) / 256, 256, 0, stream>>>(Vt);
  {
    GemmP g = {};
    g.A = Im; g.lda = KC; g.B = Pw; g.ldb = KC; g.bias = nullptr;
    g.M = 4096; g.N = DIM; g.K = KC; g.out = X; g.aux = pos_emb;
    gemm_bt<EPI_PATCH, 2><<<dim3(8, 64, 1), 256, 0, stream>>>(g);
  }

  for (int idx = 0; idx < 6; ++idx) {
    ln_k<<<MROWS, 256, 0, stream>>>(X, ln1_w + idx * DIM, ln1_b + idx * DIM, Hb);
    {
      wcvt3_k<<<(3 * NSQ4 + 255) / 256, 256, 0, stream>>>(
          q_w + (long)idx * DIM * DIM, k_w + (long)idx * DIM * DIM,
          v_w + (long)idx * DIM * DIM, Wb, NSQ4);
      cat3_k<<<12, 256, 0, stream>>>(q_b + idx * DIM, k_b + idx * DIM, v_b + idx * DIM, B3);
      GemmP g = {};
      g.A = Hb; g.lda = DIM; g.B = Wb; g.ldb = DIM; g.bias = B3;
      g.M = MROWS; g.N = 3 * DIM; g.K = DIM;
      g.out = Qb; g.out2 = Kb; g.out3 = Vt;
      gemm_bt<EPI_QKV, 4><<<dim3(24, 33, 1), 256, 0, stream>>>(g);
    }
    attn_k<<<dim3(256, 17, 1), 256, 0, stream>>>(Qb, Kb, Vt, Ctx);
    {
      GemmP g = {};
      f2b_k<<<GSQ, 256, 0, stream>>>(o_w + (long)idx * DIM * DIM, Wb, NSQ4);
      g.A = Ctx; g.lda = DIM; g.B = Wb; g.ldb = DIM;
      g.bias = o_b + idx * DIM; g.M = MROWS; g.N = DIM; g.K = DIM; g.out = X;
      gemm_bt<EPI_RES, 2><<<dim3(8, 65, 1), 256, 0, stream>>>(g);
    }
    ln_k<<<MROWS, 256, 0, stream>>>(X, ln2_w + idx * DIM, ln2_b + idx * DIM, Hb);
    {
      GemmP g = {};
      f2b_k<<<GFF, 256, 0, stream>>>(fc1_w + (long)idx * FFDIM * DIM, Wb, NFF4);
      g.A = Hb; g.lda = DIM; g.B = Wb; g.ldb = DIM;
      g.bias = fc1_b + idx * FFDIM; g.M = MROWS; g.N = FFDIM; g.K = DIM; g.out = FFh;
      gemm_bt<EPI_GELU, 4><<<dim3(32, 33, 1), 256, 0, stream>>>(g);
    }
    {
      GemmP g = {};
      f2b_k<<<GFF, 256, 0, stream>>>(fc2_w + (long)idx * DIM * FFDIM, Wb, NFF4);
      g.A = FFh; g.lda = FFDIM; g.B = Wb; g.ldb = FFDIM;
      g.bias = fc2_b + idx * DIM; g.M = MROWS; g.N = DIM; g.K = FFDIM; g.out = X;
      gemm_bt<EPI_RES, 2><<<dim3(8, 65, 1), 256, 0, stream>>>(g);
    }
    // MoD top-k block: x = where(mask, x, x) == identity -> skipped
  }
  out_k<<<(MROWS * DIM / 4) / 256, 256, 0, stream>>>(X, (float*)d_out);
}